// Round 16
// baseline (1349.547 us; speedup 1.0000x reference)
//
#include <hip/hip_runtime.h>

#define GH 135
#define GW 240
#define HH 1080
#define WW 1920
#define HWPX (HH*WW)
#define NP 12
#define IT 2               // anchor block-rows per WG (i-strip)
#define JT 12              // anchor blocks (j) per WG
#define NBG 6              // anchor pairs per it-row
#define NIG 68             // ceil(GH/IT)
#define NJG 20             // GW/JT
#define TROWS (IT+8)       // 10 staged target block-rows
#define TBLK (JT+8)        // 20 staged target blocks per dy-row
#define DSTR (TBLK*64+8)   // 1288 dw: 2-quad row rotation (r12 conflict fix)
#define UNITS_ROW (TBLK*16)// 320 16B-units per dy-row (= exactly 5 waves)
#define UNITS_TOT (TROWS*UNITS_ROW) // 3200
#define NTHR 256
#define NACT 216           // 9 dy * (2 it * 6 bg * 2 yh)
#define TT_DW (TROWS*DSTR) // 12880 dw = 51520 B -> 3 WG/CU (proven r12)
#define NWG (NIG*NJG)      // 1360 = 8*170 (XCD-exact)

// Round-16 = r12 champion (236us) with the SSD chain rewritten in PACKED FP32.
// Rationale: 4 structural variants (r11/r12/r13/r15) all converge 236-247us;
// models show no pipe >50% -> per-wave dependency duty-cycle bound. The one
// untouched term is consume-phase VALU issue count. ext_vector_type(4)
// arithmetic lowers to v_pk_{sub,mul,fma}_f32 on gfx950 (2 flops/lane/inst):
// 8-px chain = 8 pk ops + 3 scalar adds (~26 wave-cyc) vs 16 scalar ops (~36).
// Numerics: same fp32 ops at same 8-px granularity; only intra-chain summation
// order changes (pairwise) — error ~1e-7/chain, f64 accumulate + tie order
// unchanged (argmin-exact proven r1-r15).
// Occupancy law (fit r5-r10): (256,3) -> VGPR cap 85; this inner loop ~80.

typedef float v4f __attribute__((ext_vector_type(4)));

#define CHAINPK(A0, A1, T0, T1, ACC) do { \
    v4f _d0 = (A0) - (T0); \
    v4f _d1 = (A1) - (T1); \
    v4f _p  = _d0 * _d0; \
    _p = __builtin_elementwise_fma(_d1, _d1, _p); \
    (ACC) += (double)((_p.x + _p.y) + (_p.z + _p.w)); } while(0)

__device__ __forceinline__ void async_copy16(const float* gp, float* lp) {
#if __has_builtin(__builtin_amdgcn_global_load_lds)
    __builtin_amdgcn_global_load_lds(
        (const __attribute__((address_space(1))) void*)gp,
        (__attribute__((address_space(3))) void*)lp, 16, 0, 0);
#else
    *(float4*)lp = *(const float4*)gp;
#endif
}

__global__ void __launch_bounds__(NTHR, 3)
hbma_cost_kernel(const float* __restrict__ A, const float* __restrict__ T,
                 int* __restrict__ bestidx) {
    extern __shared__ float lds[];
    float* Tt = lds;

    // XCD swizzle: 1360 WGs = 8 XCDs x 170
    const int lin = blockIdx.x;
    const int g   = (lin & 7) * (NWG / 8) + (lin >> 3);
    const int ig  = g % NIG, jg = g / NIG;
    const int i0  = ig * IT;
    const int j0  = jg * JT;

    const int tid = threadIdx.x;
    const int dy  = tid / 24;          // 0..8
    const int rem = tid % 24;
    const int it  = rem / 12;          // 0..1
    const int r2  = rem % 12;
    const int bg  = r2 >> 1;           // 0..5 (anchor pair)
    const int yh  = r2 & 1;            // y-half
    const bool act = (tid < NACT);
    const int i   = i0 + it;
    const int gi  = i + dy - 4;
    const bool dyValid = act && (i < GH) && (gi >= 0) && (gi < GH);
    const int dr  = it + dy;           // staged row index 0..9

    int xq[5];                         // per p-pair h: 4*((bg+h)&7) ^ 16*yh
#pragma unroll
    for (int h = 0; h < 5; ++h) xq[h] = (((bg + h) & 7) * 4) ^ (yh << 4);

    double acc0[9], acc1[9];
#pragma unroll
    for (int d = 0; d < 9; ++d) { acc0[d] = 0.0; acc1[d] = 0.0; }

    const int gy0 = (i0 - 4) * 8;
    const int gx0 = (j0 - 4) * 8;

    for (int q = 0; q < NP; ++q) {
        const float* Tq = T + (size_t)q * HWPX;
        const float* Aq = A + (size_t)q * HWPX;
        __syncthreads();               // prev compute done before LDS overwrite
        // ---- stage target halo: async DMA, linear dest units (5 whole waves
        //      per row), inverse-swizzled + clamped global src (proven r11) ----
        for (int w = tid; w < UNITS_TOT; w += NTHR) {
            const int dyr = w / UNITS_ROW;
            const int u   = w - dyr * UNITS_ROW;
            const int blk = u >> 4, v = u & 15;
            const int kb  = (blk >> 1) & 7;
            const int yh2 = v >> 3;
            const int m3  = (v & 7) ^ kb ^ (yh2 << 2);
            const int y   = (yh2 << 2) + (m3 >> 1);
            const int xh4 = m3 & 1;
            int gy = gy0 + dyr * 8 + y;
            int gx = gx0 + blk * 8 + xh4 * 4;
            gy = min(max(gy, 0), HH - 1);
            gx = min(max(gx, 0), WW - 4);
            async_copy16(Tq + (size_t)gy * WW + gx, Tt + dyr * DSTR + u * 4);
        }
        // ---- anchor rows -> registers (issue overlaps in-flight DMA) ----
        v4f ar[2][4][2];
        if (act && i < GH) {
#pragma unroll
            for (int a2 = 0; a2 < 2; ++a2) {
                const float* ap = Aq + (size_t)(j0 + 2 * bg + a2) * 8;
#pragma unroll
                for (int yi = 0; yi < 4; ++yi) {
                    const float* row = ap + (size_t)(i * 8 + yh * 4 + yi) * WW;
                    ar[a2][yi][0] = *(const v4f*)(row);
                    ar[a2][yi][1] = *(const v4f*)(row + 4);
                }
            }
        }
        __syncthreads();               // auto vmcnt(0): DMA landed
        // ---- SSD: sliding 10-block window serves 2 anchors x 9 dx ----
        if (dyValid) {
            const float* tb = Tt + dr * DSTR + bg * 128 + yh * 32;
#pragma unroll
            for (int yi = 0; yi < 4; ++yi) {
#pragma unroll
                for (int ph = 0; ph < 2; ++ph) {       // p-chunks of 5: 10-deep ds ILP
                    v4f tw0[5], tw1[5];
#pragma unroll
                    for (int pp = 0; pp < 5; ++pp) {
                        const int p  = ph * 5 + pp;
                        const int o0 = (yi * 8) ^ xq[p >> 1];
                        tw0[pp] = *(const v4f*)(tb + p * 64 + o0);
                        tw1[pp] = *(const v4f*)(tb + p * 64 + (o0 ^ 4));
                    }
#pragma unroll
                    for (int pp = 0; pp < 5; ++pp) {
                        const int p = ph * 5 + pp;
                        if (p < 9) CHAINPK(ar[0][yi][0], ar[0][yi][1], tw0[pp], tw1[pp], acc0[p]);
                        if (p > 0) CHAINPK(ar[1][yi][0], ar[1][yi][1], tw0[pp], tw1[pp], acc1[p - 1]);
                    }
                }
            }
        }
    }
    // ---- y-half merge via LDS (aliases Tt, barrier-protected) ----
    __syncthreads();
    double* yred = (double*)lds;                     // 108 pairs * 18 f64 = 3888 dw
    const int pairId = (it * NBG + bg) * 9 + dy;
    if (act && yh == 1) {
        double* d = yred + pairId * 18;
#pragma unroll
        for (int k = 0; k < 9; ++k) { d[k] = acc0[k]; d[9 + k] = acc1[k]; }
    }
    __syncthreads();
    double* redc = (double*)(lds + 8192);            // 216 f64 = 432 dw
    int*    redk = (int*)(lds + 8192 + 432);         // 216 int
    if (act && yh == 0) {
        const double* d = yred + pairId * 18;
#pragma unroll
        for (int k = 0; k < 9; ++k) { acc0[k] += d[k]; acc1[k] += d[9 + k]; }
        // stage-1 argmin over dx (ascending, strict < -> first-k ties)
#pragma unroll
        for (int a2 = 0; a2 < 2; ++a2) {
            double bc = 1e300; int bk = -1;
            const int jb = j0 + 2 * bg + a2;
#pragma unroll
            for (int dxi = 0; dxi < 9; ++dxi) {
                const int gj = jb + dxi - 4;
                const double c = a2 ? acc1[dxi] : acc0[dxi];
                if (dyValid && gj >= 0 && gj < GW && c < bc) { bc = c; bk = dy * 9 + dxi; }
            }
            redc[(it * 9 + dy) * JT + 2 * bg + a2] = bc;
            redk[(it * 9 + dy) * JT + 2 * bg + a2] = bk;
        }
    }
    __syncthreads();
    // ---- stage-2 argmin over dy (ascending, strict <) ----
    if (tid < IT * JT) {
        const int it2 = tid / JT, jt = tid % JT;
        if (i0 + it2 < GH) {
            double c = 1e300; int k = -1;
#pragma unroll
            for (int dyi = 0; dyi < 9; ++dyi) {
                const double v = redc[(it2 * 9 + dyi) * JT + jt];
                if (v < c) { c = v; k = redk[(it2 * 9 + dyi) * JT + jt]; }
            }
            const int dyi = k / 9, dxi = k % 9;
            const int bi = i0 + it2 + dyi - 4;
            const int bj = j0 + jt + dxi - 4;
            bestidx[(i0 + it2) * GW + j0 + jt] = (bi << 8) | bj;
        }
    }
}

__global__ void __launch_bounds__(256) hbma_gather_kernel(const float* __restrict__ A,
                                                          const int* __restrict__ bestidx,
                                                          float* __restrict__ out) {
    const int tid = blockIdx.x * 256 + threadIdx.x;
    const int q   = tid / (HWPX / 4);
    const int rem = tid % (HWPX / 4);
    const int py  = rem / (WW / 4);
    const int c4  = rem % (WW / 4);
    const int i = py >> 3, y = py & 7;
    const int j = c4 >> 1, xh = (c4 & 1) * 4;
    const int idx = bestidx[i * GW + j];
    const int bi = idx >> 8, bj = idx & 255;
    const float4 v = *(const float4*)(A + (size_t)q * HWPX + (size_t)(bi * 8 + y) * WW + bj * 8 + xh);
    *(float4*)(out + (size_t)q * HWPX + (size_t)py * WW + c4 * 4) = v;
}

extern "C" void kernel_launch(void* const* d_in, const int* in_sizes, int n_in,
                              void* d_out, int out_size, void* d_ws, size_t ws_size,
                              hipStream_t stream) {
    const float* A = (const float*)d_in[0];
    const float* T = (const float*)d_in[1];
    float* out = (float*)d_out;
    int* bestidx = (int*)d_ws;

    hipFuncSetAttribute((const void*)hbma_cost_kernel,
                        hipFuncAttributeMaxDynamicSharedMemorySize, TT_DW * 4);

    hipLaunchKernelGGL(hbma_cost_kernel, dim3(NWG), dim3(NTHR), TT_DW * 4, stream,
                       A, T, bestidx);

    const int total4 = (NP * HWPX) / 4;
    hipLaunchKernelGGL(hbma_gather_kernel, dim3(total4 / 256), dim3(256), 0, stream,
                       A, bestidx, out);
}

// Round 17
// 410.829 us; speedup vs baseline: 3.2849x; 3.2849x over previous
//
#include <hip/hip_runtime.h>

#define GH 135
#define GW 240
#define HH 1080
#define WW 1920
#define HWPX (HH*WW)
#define NP 12
#define IT 2               // anchor block-rows per WG (i-strip)
#define JT 12              // anchor blocks (j) per WG
#define NBG 6              // anchor pairs per it-row
#define NIG 68             // ceil(GH/IT)
#define NJG 20             // GW/JT
#define NTHR 256
#define NACT 216           // 9 dy * (2 it * 6 bg * 2 yh)
#define NWG (NIG*NJG)      // 1360 = 8*170 (XCD-exact)

// Round-17: BARRIER-FREE global-direct kernel (Common-mistake #7: don't LDS-
// stage data that cache-fits). Five LDS-staged schedules (r11-r15) plateau at
// 236-247us with no pipe >50% busy -> the stage->barrier->compute alternation
// itself is the bound. Here the main loop has ZERO __syncthreads, ZERO LDS:
// target reads hit L1/L2 directly (per-yi WG working set ~15KB fits L1; plane
// fits aggregate L2; XCD swizzle keeps neighbor halos L2-local). Waves are
// independent dataflow; 12 waves/CU + 10-load chunks hide latency.
// Occupancy law (fit r5-r10): (256,3) -> VGPR cap 85 (r11's identical consume
// loop measured 84). LDS only for the final argmin reduction (18KB static).
// Precision: scalar fp32 8-px chains + f64 accumulate, dx-then-dy ascending
// strict-< argmin (argmin-exact vs np reference, proven r1-r15).

#define CHAIN(AV0, AV1, T0, T1, ACC) do { \
    float _d = (AV0).x - (T0).x; float _s = _d*_d; \
    _d = (AV0).y - (T0).y; _s = fmaf(_d,_d,_s); \
    _d = (AV0).z - (T0).z; _s = fmaf(_d,_d,_s); \
    _d = (AV0).w - (T0).w; _s = fmaf(_d,_d,_s); \
    _d = (AV1).x - (T1).x; _s = fmaf(_d,_d,_s); \
    _d = (AV1).y - (T1).y; _s = fmaf(_d,_d,_s); \
    _d = (AV1).z - (T1).z; _s = fmaf(_d,_d,_s); \
    _d = (AV1).w - (T1).w; _s = fmaf(_d,_d,_s); \
    (ACC) += (double)_s; } while(0)

__global__ void __launch_bounds__(NTHR, 3)
hbma_cost_kernel(const float* __restrict__ A, const float* __restrict__ T,
                 int* __restrict__ bestidx) {
    // reduction-only LDS (no main-loop use)
    __shared__ double yred[108 * 18];     // per (it,bg,dy): 18 f64
    __shared__ double redc[216];
    __shared__ int    redk[216];

    // XCD swizzle: 1360 WGs = 8 XCDs x 170 (L2 halo sharing between neighbors)
    const int lin = blockIdx.x;
    const int g   = (lin & 7) * (NWG / 8) + (lin >> 3);
    const int ig  = g % NIG, jg = g / NIG;
    const int i0  = ig * IT;
    const int j0  = jg * JT;

    const int tid = threadIdx.x;
    const int dy  = tid / 24;          // 0..8
    const int rem = tid % 24;
    const int it  = rem / 12;          // 0..1
    const int r2  = rem % 12;
    const int bg  = r2 >> 1;           // 0..5 (anchor pair)
    const int yh  = r2 & 1;            // y-half
    const bool act = (tid < NACT);
    const int i   = i0 + it;
    const int gi  = i + dy - 4;
    const bool dyValid = act && (i < GH) && (gi >= 0) && (gi < GH);

    // clamped column offsets for the 10-block sliding window (q-independent;
    // static-indexed -> registers). clamp <=> both consumers' gj out of range
    // (gj == jw for a2=0 and a2=1) -> garbage slots are argmin-masked.
    int xoff[10];
#pragma unroll
    for (int p = 0; p < 10; ++p) {
        int jw = j0 + 2 * bg - 4 + p;
        jw = min(max(jw, 0), GW - 1);
        xoff[p] = jw * 8;
    }

    double acc0[9], acc1[9];
#pragma unroll
    for (int d = 0; d < 9; ++d) { acc0[d] = 0.0; acc1[d] = 0.0; }

    if (dyValid) {
        const size_t arow0 = (size_t)(i * 8 + yh * 4) * WW;       // anchor rows
        const size_t trow0 = (size_t)(gi * 8 + yh * 4) * WW;      // target rows
        const int ja = (j0 + 2 * bg) * 8;
        for (int q = 0; q < NP; ++q) {
            const float* Tq = T + (size_t)q * HWPX;
            const float* Aq = A + (size_t)q * HWPX;
#pragma unroll
            for (int yi = 0; yi < 4; ++yi) {
                const float* arow = Aq + arow0 + (size_t)yi * WW + ja;
                const float* trow = Tq + trow0 + (size_t)yi * WW;
                const float4 a00 = *(const float4*)(arow);
                const float4 a01 = *(const float4*)(arow + 4);
                const float4 a10 = *(const float4*)(arow + 8);
                const float4 a11 = *(const float4*)(arow + 12);
#pragma unroll
                for (int ph = 0; ph < 2; ++ph) {     // p-chunks of 5: 10-deep ILP
                    float4 tw0[5], tw1[5];
#pragma unroll
                    for (int pp = 0; pp < 5; ++pp) {
                        const int p = ph * 5 + pp;
                        tw0[pp] = *(const float4*)(trow + xoff[p]);
                        tw1[pp] = *(const float4*)(trow + xoff[p] + 4);
                    }
#pragma unroll
                    for (int pp = 0; pp < 5; ++pp) {
                        const int p = ph * 5 + pp;
                        if (p < 9) CHAIN(a00, a01, tw0[pp], tw1[pp], acc0[p]);
                        if (p > 0) CHAIN(a10, a11, tw0[pp], tw1[pp], acc1[p - 1]);
                    }
                }
            }
        }
    }
    // ---- y-half merge via LDS ----
    __syncthreads();
    const int pairId = (it * NBG + bg) * 9 + dy;
    if (act && yh == 1) {
        double* d = yred + pairId * 18;
#pragma unroll
        for (int k = 0; k < 9; ++k) { d[k] = acc0[k]; d[9 + k] = acc1[k]; }
    }
    __syncthreads();
    if (act && yh == 0) {
        const double* d = yred + pairId * 18;
#pragma unroll
        for (int k = 0; k < 9; ++k) { acc0[k] += d[k]; acc1[k] += d[9 + k]; }
        // stage-1 argmin over dx (ascending, strict < -> first-k ties)
#pragma unroll
        for (int a2 = 0; a2 < 2; ++a2) {
            double bc = 1e300; int bk = -1;
            const int jb = j0 + 2 * bg + a2;
#pragma unroll
            for (int dxi = 0; dxi < 9; ++dxi) {
                const int gj = jb + dxi - 4;
                const double c = a2 ? acc1[dxi] : acc0[dxi];
                if (dyValid && gj >= 0 && gj < GW && c < bc) { bc = c; bk = dy * 9 + dxi; }
            }
            redc[(it * 9 + dy) * JT + 2 * bg + a2] = bc;
            redk[(it * 9 + dy) * JT + 2 * bg + a2] = bk;
        }
    }
    __syncthreads();
    // ---- stage-2 argmin over dy (ascending, strict <) ----
    if (tid < IT * JT) {
        const int it2 = tid / JT, jt = tid % JT;
        if (i0 + it2 < GH) {
            double c = 1e300; int k = -1;
#pragma unroll
            for (int dyi = 0; dyi < 9; ++dyi) {
                const double v = redc[(it2 * 9 + dyi) * JT + jt];
                if (v < c) { c = v; k = redk[(it2 * 9 + dyi) * JT + jt]; }
            }
            const int dyi = k / 9, dxi = k % 9;
            const int bi = i0 + it2 + dyi - 4;
            const int bj = j0 + jt + dxi - 4;
            bestidx[(i0 + it2) * GW + j0 + jt] = (bi << 8) | bj;
        }
    }
}

__global__ void __launch_bounds__(256) hbma_gather_kernel(const float* __restrict__ A,
                                                          const int* __restrict__ bestidx,
                                                          float* __restrict__ out) {
    const int tid = blockIdx.x * 256 + threadIdx.x;
    const int q   = tid / (HWPX / 4);
    const int rem = tid % (HWPX / 4);
    const int py  = rem / (WW / 4);
    const int c4  = rem % (WW / 4);
    const int i = py >> 3, y = py & 7;
    const int j = c4 >> 1, xh = (c4 & 1) * 4;
    const int idx = bestidx[i * GW + j];
    const int bi = idx >> 8, bj = idx & 255;
    const float4 v = *(const float4*)(A + (size_t)q * HWPX + (size_t)(bi * 8 + y) * WW + bj * 8 + xh);
    *(float4*)(out + (size_t)q * HWPX + (size_t)py * WW + c4 * 4) = v;
}

extern "C" void kernel_launch(void* const* d_in, const int* in_sizes, int n_in,
                              void* d_out, int out_size, void* d_ws, size_t ws_size,
                              hipStream_t stream) {
    const float* A = (const float*)d_in[0];
    const float* T = (const float*)d_in[1];
    float* out = (float*)d_out;
    int* bestidx = (int*)d_ws;

    hipLaunchKernelGGL(hbma_cost_kernel, dim3(NWG), dim3(NTHR), 0, stream,
                       A, T, bestidx);

    const int total4 = (NP * HWPX) / 4;
    hipLaunchKernelGGL(hbma_gather_kernel, dim3(total4 / 256), dim3(256), 0, stream,
                       A, bestidx, out);
}

// Round 18
// 244.910 us; speedup vs baseline: 5.5104x; 1.6775x over previous
//
#include <hip/hip_runtime.h>

#define GH 135
#define GW 240
#define HH 1080
#define WW 1920
#define HWPX (HH*WW)
#define NP 12
#define IT 2               // anchor block-rows per WG (i-strip)
#define JT 12              // anchor blocks (j) per WG
#define NBG 6              // anchor pairs per it-row
#define NIG 68             // ceil(GH/IT)
#define NJG 20             // GW/JT
#define TROWS (IT+8)       // 10 staged target block-rows
#define TBLK (JT+8)        // 20 staged target blocks per dy-row
#define DSTR (TBLK*64+8)   // 1288 dw: 2-quad row rotation (r12 conflict fix)
#define UNITS_ROW (TBLK*16)// 320 16B-units per dy-row (= exactly 5 waves)
#define UNITS_TOT (TROWS*UNITS_ROW) // 3200
#define NTHR 256
#define NACT 216           // 9 dy * (2 it * 6 bg * 2 yh)
#define TT_DW (TROWS*DSTR) // 12880 dw = 51520 B; x2 WG = 103KB <= 160KB
#define NWG (NIG*NJG)      // 1360 = 8*170 (XCD-exact)

// Round-18 = r12 champion + explicit software-pipelined consume at (256,2).
// r11-r15 plateau diagnosis: LDS pipe 43%, VALU 29%, ~30% idle — per-wave
// serialization of {ds_read batch -> wait -> chains} at zero reg headroom
// ((256,3) cap 85, used 84). Fix: cap 128 (occupancy 12->8 waves/CU, proven
// free by r13) + declarative 2-buffer pipeline: each ds batch is in flight
// under the previous batch's chains; anchor global loads overlap the first
// ds batch (vmcnt/lgkmcnt independent). r16 lesson: NO ext_vector packed
// math (scratch explosion); scalar CHAIN kept byte-identical.
// r17 lesson: global-direct is worse (L1/TA ~half LDS throughput) — keep LDS.
// Staging: async global_load_lds, linear dest units (5 whole waves/row),
// inverse-swizzled + clamped src (r11). Swizzle (bijective, r5/r12):
//   stored(blk,y,xh) = blk*64 + ((y*8+xh) ^ 4*kb ^ 16*(y>>2)), kb=(blk>>1)&7

// 8-px fp32 chain + f64 accumulate (argmin-exact vs np reference, r1-r17)
#define CHAIN(AV0, AV1, T0, T1, ACC) do { \
    float _d = (AV0).x - (T0).x; float _s = _d*_d; \
    _d = (AV0).y - (T0).y; _s = fmaf(_d,_d,_s); \
    _d = (AV0).z - (T0).z; _s = fmaf(_d,_d,_s); \
    _d = (AV0).w - (T0).w; _s = fmaf(_d,_d,_s); \
    _d = (AV1).x - (T1).x; _s = fmaf(_d,_d,_s); \
    _d = (AV1).y - (T1).y; _s = fmaf(_d,_d,_s); \
    _d = (AV1).z - (T1).z; _s = fmaf(_d,_d,_s); \
    _d = (AV1).w - (T1).w; _s = fmaf(_d,_d,_s); \
    (ACC) += (double)_s; } while(0)

// load CNT tw pairs for chunk starting at P0 (all indices compile-time)
#define LOADC(T0A, T1A, YI, P0, CNT) do { \
    _Pragma("unroll") \
    for (int pp = 0; pp < (CNT); ++pp) { \
        const int p  = (P0) + pp; \
        const int o0 = ((YI) * 8) ^ xq[p >> 1]; \
        T0A[pp] = *(const float4*)(tb + p * 64 + o0); \
        T1A[pp] = *(const float4*)(tb + p * 64 + (o0 ^ 4)); \
    } } while(0)

// consume CNT tw pairs of chunk at P0 with anchors aw0..aw3
#define CONSC(T0A, T1A, P0, CNT) do { \
    _Pragma("unroll") \
    for (int pp = 0; pp < (CNT); ++pp) { \
        const int p = (P0) + pp; \
        if (p < 9) CHAIN(aw0, aw1, T0A[pp], T1A[pp], acc0[p]); \
        if (p > 0) CHAIN(aw2, aw3, T0A[pp], T1A[pp], acc1[p - 1]); \
    } } while(0)

#define YIBODY(YI) do { \
    const float* arow_ = Aq + arow0 + (size_t)(YI) * WW + ja; \
    aw0 = *(const float4*)(arow_);      aw1 = *(const float4*)(arow_ + 4); \
    aw2 = *(const float4*)(arow_ + 8);  aw3 = *(const float4*)(arow_ + 12); \
    LOADC(twA0, twA1, YI, 0, 4); \
    LOADC(twB0, twB1, YI, 4, 4); \
    CONSC(twA0, twA1, 0, 4); \
    LOADC(twA0, twA1, YI, 8, 2); \
    CONSC(twB0, twB1, 4, 4); \
    CONSC(twA0, twA1, 8, 2); \
} while(0)

__device__ __forceinline__ void async_copy16(const float* gp, float* lp) {
#if __has_builtin(__builtin_amdgcn_global_load_lds)
    __builtin_amdgcn_global_load_lds(
        (const __attribute__((address_space(1))) void*)gp,
        (__attribute__((address_space(3))) void*)lp, 16, 0, 0);
#else
    *(float4*)lp = *(const float4*)gp;
#endif
}

__global__ void __launch_bounds__(NTHR, 2)
hbma_cost_kernel(const float* __restrict__ A, const float* __restrict__ T,
                 int* __restrict__ bestidx) {
    extern __shared__ float lds[];
    float* Tt = lds;

    // XCD swizzle: 1360 WGs = 8 XCDs x 170
    const int lin = blockIdx.x;
    const int g   = (lin & 7) * (NWG / 8) + (lin >> 3);
    const int ig  = g % NIG, jg = g / NIG;
    const int i0  = ig * IT;
    const int j0  = jg * JT;

    const int tid = threadIdx.x;
    const int dy  = tid / 24;          // 0..8
    const int rem = tid % 24;
    const int it  = rem / 12;          // 0..1
    const int r2  = rem % 12;
    const int bg  = r2 >> 1;           // 0..5 (anchor pair)
    const int yh  = r2 & 1;            // y-half
    const bool act = (tid < NACT);
    const int i   = i0 + it;
    const int gi  = i + dy - 4;
    const bool dyValid = act && (i < GH) && (gi >= 0) && (gi < GH);
    const int dr  = it + dy;           // staged row index 0..9

    int xq[5];                         // per p-pair h: 4*((bg+h)&7) ^ 16*yh
#pragma unroll
    for (int h = 0; h < 5; ++h) xq[h] = (((bg + h) & 7) * 4) ^ (yh << 4);

    double acc0[9], acc1[9];
#pragma unroll
    for (int d = 0; d < 9; ++d) { acc0[d] = 0.0; acc1[d] = 0.0; }

    const int gy0 = (i0 - 4) * 8;
    const int gx0 = (j0 - 4) * 8;
    const size_t arow0 = (size_t)(i * 8 + yh * 4) * WW;
    const int ja = (j0 + 2 * bg) * 8;

    for (int q = 0; q < NP; ++q) {
        const float* Tq = T + (size_t)q * HWPX;
        const float* Aq = A + (size_t)q * HWPX;
        __syncthreads();               // prev compute done before LDS overwrite
        // ---- stage target halo: async DMA, linear dest units, clamped src ----
        for (int w = tid; w < UNITS_TOT; w += NTHR) {
            const int dyr = w / UNITS_ROW;
            const int u   = w - dyr * UNITS_ROW;
            const int blk = u >> 4, v = u & 15;
            const int kb  = (blk >> 1) & 7;
            const int yh2 = v >> 3;
            const int m3  = (v & 7) ^ kb ^ (yh2 << 2);
            const int y   = (yh2 << 2) + (m3 >> 1);
            const int xh4 = m3 & 1;
            int gy = gy0 + dyr * 8 + y;
            int gx = gx0 + blk * 8 + xh4 * 4;
            gy = min(max(gy, 0), HH - 1);
            gx = min(max(gx, 0), WW - 4);
            async_copy16(Tq + (size_t)gy * WW + gx, Tt + dyr * DSTR + u * 4);
        }
        __syncthreads();               // auto vmcnt(0): DMA landed
        // ---- SSD: software-pipelined 2-buffer consume (loads fly under chains) ----
        if (dyValid) {
            const float* tb = Tt + dr * DSTR + bg * 128 + yh * 32;
            float4 twA0[4], twA1[4], twB0[4], twB1[4];
            float4 aw0, aw1, aw2, aw3;
            YIBODY(0);
            YIBODY(1);
            YIBODY(2);
            YIBODY(3);
        }
    }
    // ---- y-half merge via LDS (aliases Tt, barrier-protected) ----
    __syncthreads();
    double* yred = (double*)lds;                     // 108 pairs * 18 f64 = 3888 dw
    const int pairId = (it * NBG + bg) * 9 + dy;
    if (act && yh == 1) {
        double* d = yred + pairId * 18;
#pragma unroll
        for (int k = 0; k < 9; ++k) { d[k] = acc0[k]; d[9 + k] = acc1[k]; }
    }
    __syncthreads();
    double* redc = (double*)(lds + 8192);            // 216 f64 = 432 dw
    int*    redk = (int*)(lds + 8192 + 432);         // 216 int
    if (act && yh == 0) {
        const double* d = yred + pairId * 18;
#pragma unroll
        for (int k = 0; k < 9; ++k) { acc0[k] += d[k]; acc1[k] += d[9 + k]; }
        // stage-1 argmin over dx (ascending, strict < -> first-k ties)
#pragma unroll
        for (int a2 = 0; a2 < 2; ++a2) {
            double bc = 1e300; int bk = -1;
            const int jb = j0 + 2 * bg + a2;
#pragma unroll
            for (int dxi = 0; dxi < 9; ++dxi) {
                const int gj = jb + dxi - 4;
                const double c = a2 ? acc1[dxi] : acc0[dxi];
                if (dyValid && gj >= 0 && gj < GW && c < bc) { bc = c; bk = dy * 9 + dxi; }
            }
            redc[(it * 9 + dy) * JT + 2 * bg + a2] = bc;
            redk[(it * 9 + dy) * JT + 2 * bg + a2] = bk;
        }
    }
    __syncthreads();
    // ---- stage-2 argmin over dy (ascending, strict <) ----
    if (tid < IT * JT) {
        const int it2 = tid / JT, jt = tid % JT;
        if (i0 + it2 < GH) {
            double c = 1e300; int k = -1;
#pragma unroll
            for (int dyi = 0; dyi < 9; ++dyi) {
                const double v = redc[(it2 * 9 + dyi) * JT + jt];
                if (v < c) { c = v; k = redk[(it2 * 9 + dyi) * JT + jt]; }
            }
            const int dyi = k / 9, dxi = k % 9;
            const int bi = i0 + it2 + dyi - 4;
            const int bj = j0 + jt + dxi - 4;
            bestidx[(i0 + it2) * GW + j0 + jt] = (bi << 8) | bj;
        }
    }
}

__global__ void __launch_bounds__(256) hbma_gather_kernel(const float* __restrict__ A,
                                                          const int* __restrict__ bestidx,
                                                          float* __restrict__ out) {
    const int tid = blockIdx.x * 256 + threadIdx.x;
    const int q   = tid / (HWPX / 4);
    const int rem = tid % (HWPX / 4);
    const int py  = rem / (WW / 4);
    const int c4  = rem % (WW / 4);
    const int i = py >> 3, y = py & 7;
    const int j = c4 >> 1, xh = (c4 & 1) * 4;
    const int idx = bestidx[i * GW + j];
    const int bi = idx >> 8, bj = idx & 255;
    const float4 v = *(const float4*)(A + (size_t)q * HWPX + (size_t)(bi * 8 + y) * WW + bj * 8 + xh);
    *(float4*)(out + (size_t)q * HWPX + (size_t)py * WW + c4 * 4) = v;
}

extern "C" void kernel_launch(void* const* d_in, const int* in_sizes, int n_in,
                              void* d_out, int out_size, void* d_ws, size_t ws_size,
                              hipStream_t stream) {
    const float* A = (const float*)d_in[0];
    const float* T = (const float*)d_in[1];
    float* out = (float*)d_out;
    int* bestidx = (int*)d_ws;

    hipFuncSetAttribute((const void*)hbma_cost_kernel,
                        hipFuncAttributeMaxDynamicSharedMemorySize, TT_DW * 4);

    hipLaunchKernelGGL(hbma_cost_kernel, dim3(NWG), dim3(NTHR), TT_DW * 4, stream,
                       A, T, bestidx);

    const int total4 = (NP * HWPX) / 4;
    hipLaunchKernelGGL(hbma_gather_kernel, dim3(total4 / 256), dim3(256), 0, stream,
                       A, bestidx, out);
}